// Round 1
// 410.856 us; speedup vs baseline: 1.3033x; 1.3033x over previous
//
#include <hip/hip_runtime.h>
#include <math.h>

#define BB 16
#define TT 512
#define IND 128
#define HH 256
#define DD 8
#define EPSF 1e-5f

typedef _Float16 h2_t __attribute__((ext_vector_type(2)));

__device__ __forceinline__ float fast_tanh(float x) {
    x = fminf(fmaxf(x, -15.f), 15.f);
    const float e = __expf(2.f * x);
    return __fdividef(e - 1.f, e + 1.f);
}

// quad_perm XOR swaps on the VALU pipe (no LDS traffic)
__device__ __forceinline__ float dpp_xor1(float x) {
    int i = __builtin_bit_cast(int, x);
    i = __builtin_amdgcn_update_dpp(i, i, 0xB1, 0xF, 0xF, true);  // {1,0,3,2}
    return __builtin_bit_cast(float, i);
}
__device__ __forceinline__ float dpp_xor2(float x) {
    int i = __builtin_bit_cast(int, x);
    i = __builtin_amdgcn_update_dpp(i, i, 0x4E, 0xF, 0xF, true);  // {2,3,0,1}
    return __builtin_bit_cast(float, i);
}

// ---------------- K1: x_proj[b,t,j] = y[b,t,:]·W_ih[j,:] + b_ih[j] + b_hh[j] ----------------
__global__ __launch_bounds__(512, 4) void xproj_kernel(
    const float* __restrict__ y, const float* __restrict__ W_ih,
    const float* __restrict__ b_ih, const float* __restrict__ b_hh,
    float* __restrict__ xp)
{
    __shared__ __align__(16) float ylds[IND];
    const int tid = threadIdx.x;
    const int j = tid >> 1;
    const int k4 = (tid & 1) * 4;

    float4 w[16];
    const float* wr = W_ih + (size_t)j * IND + k4;
#pragma unroll
    for (int i = 0; i < 16; ++i) w[i] = *(const float4*)(wr + i * 8);
#pragma unroll
    for (int i = 0; i < 16; ++i)
        asm volatile("" : "+v"(w[i].x), "+v"(w[i].y), "+v"(w[i].z), "+v"(w[i].w));
    const float bias = b_ih[j] + b_hh[j];

    const int row0 = blockIdx.x * 16;
    for (int r = 0; r < 16; ++r) {
        const int row = row0 + r;
        if (tid < IND / 4) ((float4*)ylds)[tid] = ((const float4*)(y + (size_t)row * IND))[tid];
        __syncthreads();
        float a0 = 0.f, a1 = 0.f, a2 = 0.f, a3 = 0.f;
#pragma unroll
        for (int i = 0; i < 16; ++i) {
            const float4 hv = *(const float4*)(ylds + i * 8 + k4);
            a0 = fmaf(hv.x, w[i].x, a0);
            a1 = fmaf(hv.y, w[i].y, a1);
            a2 = fmaf(hv.z, w[i].z, a2);
            a3 = fmaf(hv.w, w[i].w, a3);
        }
        float acc = (a0 + a1) + (a2 + a3);
        acc += __shfl_xor(acc, 1);
        if ((tid & 1) == 0) xp[(size_t)row * HH + j] = acc + bias;
        __syncthreads();
    }
}

// ---------------- K2: RNN scan (blocks 0..15) + prec zero-fill (blocks 16..) ----------------
// Scan block: 256 threads = 64 j-groups x 4 k-slices. Each thread owns 4 output columns
// (j0+64m) with 128 pinned f16-pair weight VGPRs, so its single 128-B LDS slice read is
// reused 4x (LDS reads/step: 128 -> 32 b128). Quad reduce via DPP (VALU pipe, no LDS).
// Barrier is lgkmcnt-only (raw s_barrier) so the 4-deep xp register prefetch stays in
// flight across steps (no vmcnt(0) drain per step).
__global__ __launch_bounds__(256, 2) void scan_fill_kernel(
    const float* __restrict__ xp, const float* __restrict__ W_hh,
    float* __restrict__ enc, float* __restrict__ prec)
{
    if (blockIdx.x >= BB) {
        const size_t n4 = (size_t)BB * DD * TT * TT / 4;
        const float4 z = make_float4(0.f, 0.f, 0.f, 0.f);
        float4* p4 = (float4*)prec;
        size_t idx = (size_t)(blockIdx.x - BB) * blockDim.x + threadIdx.x;
        const size_t stride = (size_t)(gridDim.x - BB) * blockDim.x;
        for (; idx < n4; idx += stride) p4[idx] = z;
        return;
    }

    const int b = blockIdx.x;
    const int tid = threadIdx.x;
    const int j0 = tid >> 2;       // 0..63
    const int k  = tid & 3;        // k-slice AND which of the 4 owned columns this lane keeps
    const int jw = j0 + 64 * k;    // the column this lane writes

    // each k-slice: 64 halves = 128 B, padded to 144 B so the 4 distinct wave
    // addresses land on different bank octets
    __shared__ __align__(16) char hbufA[4 * 144];
    __shared__ __align__(16) char hbufB[4 * 144];

    // weights: rows j0+64m, slice [k*64, k*64+64), as 32 f16-pairs each (128 VGPRs)
    h2_t w[4][32];
#pragma unroll
    for (int m = 0; m < 4; ++m) {
        const float* wr = W_hh + (size_t)(j0 + 64 * m) * HH + (size_t)k * 64;
#pragma unroll
        for (int q = 0; q < 16; ++q) {
            const float4 f = ((const float4*)wr)[q];
            h2_t v0; v0.x = (_Float16)f.x; v0.y = (_Float16)f.y;
            h2_t v1; v1.x = (_Float16)f.z; v1.y = (_Float16)f.w;
            w[m][2 * q]     = v0;
            w[m][2 * q + 1] = v1;
        }
    }
#pragma unroll
    for (int m = 0; m < 4; ++m)
#pragma unroll
        for (int i = 0; i < 32; ++i) {
            int tmp = __builtin_bit_cast(int, w[m][i]);
            asm volatile("" : "+v"(tmp));
            w[m][i] = __builtin_bit_cast(h2_t, tmp);
        }

    // zero-init hbufA (pads don't matter: never read)
    if (tid < 128) {
        const int m = 2 * tid;
        h2_t z; z.x = (_Float16)0.f; z.y = (_Float16)0.f;
        *(h2_t*)(hbufA + (m >> 6) * 144 + (m & 63) * 2) = z;
    }

    const float* xpb = xp + (size_t)b * TT * HH;
    float* encb = enc + (size_t)b * TT * HH;

    // 4-deep rotating register prefetch of xp (statically indexed via unroll)
    float xbuf[4];
#pragma unroll
    for (int s = 0; s < 4; ++s) xbuf[s] = xpb[(size_t)s * HH + jw];

    __syncthreads();  // once: init barrier (vmcnt drain here is fine)

    const char* hrd = hbufA;
    char* hwr = hbufB;

    for (int tb = 0; tb < TT; tb += 4) {
#pragma unroll
        for (int s = 0; s < 4; ++s) {
            const int t = tb + s;
            const float xc = xbuf[s];
            {   // issue prefetch for t+4 immediately (consumed 4 barriers later)
                const int tp = (t + 4 < TT) ? (t + 4) : (TT - 1);
                xbuf[s] = xpb[(size_t)tp * HH + jw];
            }

            float a0 = 0.f, a1 = 0.f, a2 = 0.f, a3 = 0.f;  // one acc per owned column
            const float4* hp = (const float4*)(hrd + k * 144);
#pragma unroll
            for (int i = 0; i < 8; ++i) {
                union { float4 f4; h2_t h[4]; } u;
                u.f4 = hp[i];
#pragma unroll
                for (int q = 0; q < 4; ++q) {
                    a0 = __builtin_amdgcn_fdot2(u.h[q], w[0][4 * i + q], a0, false);
                    a1 = __builtin_amdgcn_fdot2(u.h[q], w[1][4 * i + q], a1, false);
                    a2 = __builtin_amdgcn_fdot2(u.h[q], w[2][4 * i + q], a2, false);
                    a3 = __builtin_amdgcn_fdot2(u.h[q], w[3][4 * i + q], a3, false);
                }
            }
            // quad (k-lane) butterfly reduce on the VALU pipe; all 4 lanes get all 4 sums
            a0 += dpp_xor1(a0); a0 += dpp_xor2(a0);
            a1 += dpp_xor1(a1); a1 += dpp_xor2(a1);
            a2 += dpp_xor1(a2); a2 += dpp_xor2(a2);
            a3 += dpp_xor1(a3); a3 += dpp_xor2(a3);
            // lane keeps the column matching its own k
            const float p = (k & 1) ? ((k & 2) ? a3 : a1) : ((k & 2) ? a2 : a0);
            const float hn = fast_tanh(xc + p);

            // enc store: lanes cover jw = j0 + 64k -> 4 dense 64-B chunks per wave
            encb[(size_t)t * HH + jw] = hn;
            // h exchange: column jw lives in slice k at index j0
            *(_Float16*)(hwr + k * 144 + j0 * 2) = (_Float16)hn;

            // lgkm-only barrier: LDS write visible to all waves, global loads stay in flight
            asm volatile("s_waitcnt lgkmcnt(0)\n\ts_barrier" ::: "memory");
            const char* tmp = hrd; hrd = hwr; hwr = (char*)tmp;
        }
    }
}

// ---------------- K3: heads + tridiagonal fill ----------------
__global__ __launch_bounds__(256) void head_kernel(
    const float* __restrict__ enc,
    const float* __restrict__ W_mean, const float* __restrict__ b_mean,
    const float* __restrict__ W_bd, const float* __restrict__ b_bd,
    float* __restrict__ mean_out, float* __restrict__ prec)
{
    const int b = blockIdx.x >> 6;
    const int t0 = (blockIdx.x & 63) * 8;
    __shared__ __align__(16) float erow[9][HH];  // rows t0-1 .. t0+7
    __shared__ float vals[8][32];

    const int tid = threadIdx.x;
    {
        // row t0-1 (for t0==0,b==0 this reads the tail of xp — harmless, discarded)
        const float4* src = (const float4*)(enc + ((size_t)b * TT + t0) * HH - HH);
        float4* dst = (float4*)erow;
        for (int i = tid; i < 9 * (HH / 4); i += 256) dst[i] = src[i];
    }

    const int g = tid >> 3, m = tid & 7;
    const float* wrow;
    float bias;
    if (g < 8)       { wrow = W_mean + (size_t)g * HH;      bias = b_mean[g]; }
    else if (g < 24) { wrow = W_bd + (size_t)(g - 8) * HH;  bias = b_bd[g - 8]; }
    else             { wrow = W_bd + (size_t)(g - 16) * HH; bias = b_bd[g - 16]; }

    float4 wv[8];
#pragma unroll
    for (int i = 0; i < 8; ++i) wv[i] = ((const float4*)wrow)[m * 8 + i];

    __syncthreads();

    for (int r = 0; r < 8; ++r) {
        const float* src = (g >= 24) ? erow[r] : erow[r + 1];
        float acc = 0.f;
#pragma unroll
        for (int i = 0; i < 8; ++i) {
            const float4 hv = ((const float4*)src)[m * 8 + i];
            acc += wv[i].x * hv.x + wv[i].y * hv.y + wv[i].z * hv.z + wv[i].w * hv.w;
        }
        acc += __shfl_xor(acc, 1);
        acc += __shfl_xor(acc, 2);
        acc += __shfl_xor(acc, 4);
        if (m == 0) vals[r][g] = acc + bias;
    }
    __syncthreads();

    // write phase: 256 threads = 8 r-slots x 32 lanes
    const int r = tid >> 5, s = tid & 31;
    const int t = t0 + r;
    if (s < DD) {
        mean_out[((size_t)b * TT + t) * DD + s] = vals[r][s];
    } else if (s < 2 * DD) {
        const int d = s - DD;
        const float diag = vals[r][8 + d];
        const float off  = vals[r][16 + d];
        const float offp = (t > 0) ? vals[r][24 + d] : 0.f;
        const size_t rowbase = (((size_t)b * DD + d) * TT + t) * TT;
        prec[rowbase + t] = diag * diag + offp * offp + EPSF;
        if (t < TT - 1) {
            const float sv = diag * off;
            prec[rowbase + t + 1] = sv;                                 // (t, t+1)
            prec[(((size_t)b * DD + d) * TT + (t + 1)) * TT + t] = sv;  // (t+1, t)
        }
    }
}

extern "C" void kernel_launch(void* const* d_in, const int* in_sizes, int n_in,
                              void* d_out, int out_size, void* d_ws, size_t ws_size,
                              hipStream_t stream) {
    const float* y      = (const float*)d_in[0];
    const float* W_ih   = (const float*)d_in[1];
    const float* W_hh   = (const float*)d_in[2];
    const float* b_ih   = (const float*)d_in[3];
    const float* b_hh   = (const float*)d_in[4];
    const float* W_mean = (const float*)d_in[5];
    const float* b_mean = (const float*)d_in[6];
    const float* W_bd   = (const float*)d_in[7];
    const float* b_bd   = (const float*)d_in[8];

    float* out  = (float*)d_out;
    float* mean = out;                              // B*T*D floats
    float* prec = out + (size_t)BB * TT * DD;       // B*D*T*T floats

    float* xp  = (float*)d_ws;                      // B*T*H floats = 8 MB
    float* enc = xp + (size_t)BB * TT * HH;         // B*T*H floats = 8 MB

    xproj_kernel<<<512, 512, 0, stream>>>(y, W_ih, b_ih, b_hh, xp);
    scan_fill_kernel<<<1008, 256, 0, stream>>>(xp, W_hh, enc, prec);
    head_kernel<<<1024, 256, 0, stream>>>(enc, W_mean, b_mean, W_bd, b_bd, mean, prec);
}